// Round 1
// baseline (1014.101 us; speedup 1.0000x reference)
//
#include <hip/hip_runtime.h>
#include <stdint.h>

using bf16x8 = __attribute__((ext_vector_type(8))) short;
using f32x4  = __attribute__((ext_vector_type(4))) float;

__device__ __forceinline__ unsigned short f2bf(float f) {
  uint32_t x = __float_as_uint(f);
  x += 0x7fffu + ((x >> 16) & 1u);
  return (unsigned short)(x >> 16);
}
__device__ __forceinline__ float bf2f(unsigned short u) {
  return __uint_as_float(((uint32_t)u) << 16);
}
__device__ __forceinline__ float silu_f(float v) {
  return v / (1.0f + __expf(-v));
}

// ---- weight convert (f32 -> bf16 row-major [out][k]) + edge_index dtype sniff ----
__global__ void wconvert(const float* __restrict__ We1, const float* __restrict__ We2,
                         const float* __restrict__ Wn1, const float* __restrict__ Wn2,
                         const float* __restrict__ Wc1, const int* __restrict__ ei,
                         unsigned short* __restrict__ W1b, unsigned short* __restrict__ W2b,
                         unsigned short* __restrict__ N1b, unsigned short* __restrict__ N2b,
                         unsigned short* __restrict__ W3b, int* __restrict__ flag) {
  int i = blockIdx.x * 256 + threadIdx.x;      // 0..32767
  if (i < 128 * 256) {
    W1b[i] = f2bf(We1[(i >> 8) * 257 + (i & 255)]);   // We1 row stride 257; drop last col
    N1b[i] = f2bf(Wn1[i]);
  }
  if (i < 128 * 128) {
    W2b[i] = f2bf(We2[i]);
    W3b[i] = f2bf(Wc1[i]);
    N2b[i] = f2bf(Wn2[i]);
  }
  if (i == 0) {
    int allz = 1;
    for (int k = 0; k < 64; ++k) allz &= (ei[2 * k + 1] == 0);
    *flag = allz;   // 1 => indices are int64 (high words all zero)
  }
}

// ---- shared GEMM micro-tile: wave computes 16 rows x 128 cols, K = KT*32 ----
// A: LDS bf16 rows [16][astr], B: global bf16 row-major [128][bstr]
template<int KT>
__device__ __forceinline__ void mm_tile(const unsigned short* A, int astr,
                                        const unsigned short* __restrict__ B, int bstr,
                                        int lg, int lr, f32x4 acc[8]) {
#pragma unroll
  for (int k0 = 0; k0 < KT; ++k0) {
    bf16x8 a = *(const bf16x8*)(A + lr * astr + k0 * 32 + lg * 8);
#pragma unroll
    for (int n = 0; n < 8; ++n) {
      bf16x8 b = *(const bf16x8*)(B + (size_t)(n * 16 + lr) * bstr + k0 * 32 + lg * 8);
      acc[n] = __builtin_amdgcn_mfma_f32_16x16x32_bf16(a, b, acc[n], 0, 0, 0);
    }
  }
}

// ---- fused edge kernel: 64 edges/block, 4 waves, each wave owns 16 edge rows ----
__global__ __launch_bounds__(256) void edge_kernel(
    const float* __restrict__ h, const float* __restrict__ x, const int* __restrict__ ei,
    const float* __restrict__ We1, const float* __restrict__ be1,
    const float* __restrict__ be2, const float* __restrict__ bc1,
    const float* __restrict__ Wc2,
    const unsigned short* __restrict__ W1b, const unsigned short* __restrict__ W2b,
    const unsigned short* __restrict__ W3b,
    float* __restrict__ aggH, float* __restrict__ coordX, float* __restrict__ cnt,
    const int* __restrict__ flag, int E) {
  __shared__ __align__(16) unsigned short In[64][264];   // h_src|h_dst (K=256), reused as Ms2
  __shared__ __align__(16) unsigned short Ms[64][136];   // GEMM1 output
  __shared__ float sdif[64][3];
  __shared__ float sds[64];
  __shared__ int   ssrc[64], sdst[64];

  const int tid  = threadIdx.x;
  const int ebase = blockIdx.x * 64;
  const int w    = tid >> 6;
  const int lane = tid & 63;
  const int lg   = lane >> 4, lr = lane & 15;
  const int w16  = w * 16;

  if (tid < 64) {
    int e = ebase + tid;
    int s = 0, d = 0;
    if (e < E) {
      if (*flag) {
        s = (int)((const long long*)ei)[e];
        d = (int)((const long long*)ei)[(size_t)E + e];
      } else {
        s = ei[e];
        d = ei[E + e];
      }
    }
    ssrc[tid] = s; sdst[tid] = d;
    float dx = x[s * 3 + 0] - x[d * 3 + 0];
    float dy = x[s * 3 + 1] - x[d * 3 + 1];
    float dz = x[s * 3 + 2] - x[d * 3 + 2];
    sdif[tid][0] = dx; sdif[tid][1] = dy; sdif[tid][2] = dz;
    sds[tid] = dx * dx + dy * dy + dz * dz;
  }
  __syncthreads();

  // gather h[src]|h[dst] rows -> bf16 LDS
#pragma unroll
  for (int it = 0; it < 8; ++it) {
    int idx = tid + it * 256;            // 0..2047
    int e = idx >> 5, seg = idx & 31;    // 8-elem segment of the 256-wide row
    const float* p = (seg < 16) ? (h + (size_t)ssrc[e] * 128 + seg * 8)
                                : (h + (size_t)sdst[e] * 128 + (seg - 16) * 8);
    float4 a = *(const float4*)p;
    float4 b = *(const float4*)(p + 4);
    bf16x8 v;
    v[0] = f2bf(a.x); v[1] = f2bf(a.y); v[2] = f2bf(a.z); v[3] = f2bf(a.w);
    v[4] = f2bf(b.x); v[5] = f2bf(b.y); v[6] = f2bf(b.z); v[7] = f2bf(b.w);
    *(bf16x8*)&In[e][seg * 8] = v;
  }
  __syncthreads();

  // GEMM1: [64x256] x We1[:, :256]^T (+ be1 + ds*w1c), silu -> Ms
  {
    f32x4 acc[8];
#pragma unroll
    for (int n = 0; n < 8; ++n) { f32x4 z = {0.f, 0.f, 0.f, 0.f}; acc[n] = z; }
    mm_tile<8>(&In[w16][0], 264, W1b, 256, lg, lr, acc);
#pragma unroll
    for (int n = 0; n < 8; ++n) {
      int o = n * 16 + lr;
      float b1  = be1[o];
      float w1c = We1[o * 257 + 256];
#pragma unroll
      for (int r = 0; r < 4; ++r) {
        int me = lg * 4 + r;
        float v = acc[n][r] + b1 + sds[w16 + me] * w1c;
        Ms[w16 + me][o] = f2bf(silu_f(v));
      }
    }
  }

  // GEMM2: Ms x We2^T (+be2), silu -> Ms2 (reuses In arena, stride 264) [wave-local rows]
  unsigned short* Ms2 = &In[0][0];
  {
    f32x4 acc[8];
#pragma unroll
    for (int n = 0; n < 8; ++n) { f32x4 z = {0.f, 0.f, 0.f, 0.f}; acc[n] = z; }
    mm_tile<4>(&Ms[w16][0], 136, W2b, 128, lg, lr, acc);
#pragma unroll
    for (int n = 0; n < 8; ++n) {
      int o = n * 16 + lr;
      float b2 = be2[o];
#pragma unroll
      for (int r = 0; r < 4; ++r) {
        int me = w16 + lg * 4 + r;
        Ms2[(size_t)me * 264 + o] = f2bf(silu_f(acc[n][r] + b2));
      }
    }
  }

  // GEMM3: Ms2 x Wc1^T (+bc1), silu, dot with Wc2 -> cw ; coord + cnt atomics
  {
    f32x4 acc[8];
#pragma unroll
    for (int n = 0; n < 8; ++n) { f32x4 z = {0.f, 0.f, 0.f, 0.f}; acc[n] = z; }
    mm_tile<4>(Ms2 + (size_t)w16 * 264, 264, W3b, 128, lg, lr, acc);
    float pr[4] = {0.f, 0.f, 0.f, 0.f};
#pragma unroll
    for (int n = 0; n < 8; ++n) {
      int o = n * 16 + lr;
      float b3 = bc1[o];
      float wc = Wc2[o];
#pragma unroll
      for (int r = 0; r < 4; ++r) pr[r] += silu_f(acc[n][r] + b3) * wc;
    }
#pragma unroll
    for (int m = 1; m < 16; m <<= 1) {
#pragma unroll
      for (int r = 0; r < 4; ++r) pr[r] += __shfl_xor(pr[r], m);
    }
#pragma unroll
    for (int r = 0; r < 4; ++r) {
      int me = w16 + lg * 4 + r;
      int eg = ebase + me;
      if (eg < E) {
        int d = sdst[me];
        if (lr < 3)       atomicAdd(&coordX[(size_t)d * 3 + lr], sdif[me][lr] * pr[r]);
        else if (lr == 3) atomicAdd(&cnt[d], 1.0f);
      }
    }
  }
  __syncthreads();

  // agg scatter: aggH[dst] += m2
#pragma unroll
  for (int it = 0; it < 32; ++it) {
    int idx = tid + it * 256;            // 0..8191
    int e = idx >> 7, c = idx & 127;
    int eg = ebase + e;
    if (eg < E) atomicAdd(&aggH[(size_t)sdst[e] * 128 + c], bf2f(Ms2[(size_t)e * 264 + c]));
  }
}

// ---- fused node kernel: 64 nodes/block; [h|agg/cnt] GEMM -> GEMM -> +h -> LN; x_out ----
__global__ __launch_bounds__(256) void node_kernel(
    const float* __restrict__ h, const float* __restrict__ x,
    const float* __restrict__ bn1, const float* __restrict__ bn2,
    const float* __restrict__ gamma, const float* __restrict__ beta,
    const unsigned short* __restrict__ N1b, const unsigned short* __restrict__ N2b,
    float* __restrict__ aggH, float* __restrict__ coordX,
    const float* __restrict__ cnt, int N) {
  __shared__ __align__(16) unsigned short In[64][264];   // [h|agg], reused as f32 hp[64][132]
  __shared__ __align__(16) unsigned short U[64][136];
  __shared__ float scnt[64];

  const int tid  = threadIdx.x;
  const int base = blockIdx.x * 64;
  const int w    = tid >> 6;
  const int lane = tid & 63;
  const int lg   = lane >> 4, lr = lane & 15;
  const int w16  = w * 16;

  if (tid < 64) {
    int n = base + tid;
    scnt[tid] = (n < N) ? fmaxf(cnt[n], 1.0f) : 1.0f;
  }
  __syncthreads();

#pragma unroll
  for (int it = 0; it < 8; ++it) {
    int idx = tid + it * 256;
    int i = idx >> 5, seg = idx & 31;
    int n = base + i; if (n >= N) n = N - 1;
    float sc = 1.0f;
    const float* p;
    if (seg < 16) { p = h + (size_t)n * 128 + seg * 8; }
    else          { p = aggH + (size_t)n * 128 + (seg - 16) * 8; sc = 1.0f / scnt[i]; }
    float4 a = *(const float4*)p;
    float4 b = *(const float4*)(p + 4);
    bf16x8 v;
    v[0] = f2bf(a.x * sc); v[1] = f2bf(a.y * sc); v[2] = f2bf(a.z * sc); v[3] = f2bf(a.w * sc);
    v[4] = f2bf(b.x * sc); v[5] = f2bf(b.y * sc); v[6] = f2bf(b.z * sc); v[7] = f2bf(b.w * sc);
    *(bf16x8*)&In[i][seg * 8] = v;
  }
  __syncthreads();

  // GEMM n1: [h|agg] x Wn1^T (+bn1), silu -> U
  {
    f32x4 acc[8];
#pragma unroll
    for (int n = 0; n < 8; ++n) { f32x4 z = {0.f, 0.f, 0.f, 0.f}; acc[n] = z; }
    mm_tile<8>(&In[w16][0], 264, N1b, 256, lg, lr, acc);
#pragma unroll
    for (int n = 0; n < 8; ++n) {
      int o = n * 16 + lr;
      float b1 = bn1[o];
#pragma unroll
      for (int r = 0; r < 4; ++r) {
        int me = lg * 4 + r;
        U[w16 + me][o] = f2bf(silu_f(acc[n][r] + b1));
      }
    }
  }

  // GEMM n2: U x Wn2^T (+bn2 +h) -> hp (f32, In arena) [wave-local rows]
  float* hp = (float*)&In[0][0];   // stride 132 f32 (row extent == 264 ushort)
  {
    f32x4 acc[8];
#pragma unroll
    for (int n = 0; n < 8; ++n) { f32x4 z = {0.f, 0.f, 0.f, 0.f}; acc[n] = z; }
    mm_tile<4>(&U[w16][0], 136, N2b, 128, lg, lr, acc);
#pragma unroll
    for (int n = 0; n < 8; ++n) {
      int o = n * 16 + lr;
      float b2 = bn2[o];
#pragma unroll
      for (int r = 0; r < 4; ++r) {
        int me = w16 + lg * 4 + r;
        int ng = base + me; if (ng >= N) ng = N - 1;
        hp[(size_t)me * 132 + o] = acc[n][r] + b2 + h[(size_t)ng * 128 + o];
      }
    }
  }
  __syncthreads();

  // LayerNorm: 4 threads per row
  {
    int r = tid >> 2, q = tid & 3;
    int ng = base + r;
    float s = 0.f, s2 = 0.f;
#pragma unroll
    for (int j = 0; j < 32; ++j) {
      float v = hp[(size_t)r * 132 + q * 32 + j];
      s += v; s2 += v * v;
    }
    s  += __shfl_xor(s, 1);  s  += __shfl_xor(s, 2);
    s2 += __shfl_xor(s2, 1); s2 += __shfl_xor(s2, 2);
    float mu  = s * (1.0f / 128.0f);
    float var = s2 * (1.0f / 128.0f) - mu * mu;
    float rs  = rsqrtf(var + 1e-5f);
    if (ng < N) {
#pragma unroll
      for (int j = 0; j < 32; ++j) {
        int o = q * 32 + j;
        float v = (hp[(size_t)r * 132 + o] - mu) * rs * gamma[o] + beta[o];
        aggH[(size_t)ng * 128 + o] = v;
      }
    }
  }

  // x_out = x + coord_agg / cnt   (in place over coord accumulator)
  if (tid < 192) {
    int i = tid / 3, c = tid % 3;
    int n2 = base + i;
    if (n2 < N) {
      size_t off = (size_t)n2 * 3 + c;
      coordX[off] = x[off] + coordX[off] / scnt[i];
    }
  }
}

extern "C" void kernel_launch(void* const* d_in, const int* in_sizes, int n_in,
                              void* d_out, int out_size, void* d_ws, size_t ws_size,
                              hipStream_t stream) {
  const float* h    = (const float*)d_in[0];
  const float* x    = (const float*)d_in[1];
  const int*   ei   = (const int*)d_in[2];
  const float* We1  = (const float*)d_in[3];
  const float* be1  = (const float*)d_in[4];
  const float* We2  = (const float*)d_in[5];
  const float* be2  = (const float*)d_in[6];
  const float* Wn1  = (const float*)d_in[7];
  const float* bn1  = (const float*)d_in[8];
  const float* Wn2  = (const float*)d_in[9];
  const float* bn2  = (const float*)d_in[10];
  const float* Wc1  = (const float*)d_in[11];
  const float* bc1  = (const float*)d_in[12];
  const float* Wc2  = (const float*)d_in[13];
  const float* gamma = (const float*)d_in[14];
  const float* beta  = (const float*)d_in[15];

  int N = in_sizes[0] / 128;
  int E = in_sizes[2] / 2;

  float* aggH   = (float*)d_out;                       // N*128: agg accumulator -> h_out
  float* coordX = (float*)d_out + (size_t)N * 128;     // N*3:   coord accumulator -> x_out

  char* ws = (char*)d_ws;
  float* cnt = (float*)ws;
  size_t off = (((size_t)N * 4) + 255) & ~(size_t)255;
  unsigned short* W1b = (unsigned short*)(ws + off); off += 128 * 256 * 2;
  unsigned short* W2b = (unsigned short*)(ws + off); off += 128 * 128 * 2;
  unsigned short* N1b = (unsigned short*)(ws + off); off += 128 * 256 * 2;
  unsigned short* N2b = (unsigned short*)(ws + off); off += 128 * 128 * 2;
  unsigned short* W3b = (unsigned short*)(ws + off); off += 128 * 128 * 2;
  int* flag = (int*)(ws + off);

  hipMemsetAsync(d_out, 0, (size_t)out_size * 4, stream);
  hipMemsetAsync(cnt, 0, (size_t)N * 4, stream);

  wconvert<<<128, 256, 0, stream>>>(We1, We2, Wn1, Wn2, Wc1, ei,
                                    W1b, W2b, N1b, N2b, W3b, flag);
  edge_kernel<<<(E + 63) / 64, 256, 0, stream>>>(h, x, ei, We1, be1, be2, bc1, Wc2,
                                                 W1b, W2b, W3b, aggH, coordX, cnt, flag, E);
  node_kernel<<<(N + 63) / 64, 256, 0, stream>>>(h, x, bn1, bn2, gamma, beta, N1b, N2b,
                                                 aggH, coordX, cnt, N);
}